// Round 5
// baseline (634.973 us; speedup 1.0000x reference)
//
#include <hip/hip_runtime.h>
#include <hip/hip_bf16.h>

#define NPTS 262144              // output rows (2^18)
#define MRB  131072              // rulebook entries per offset (2^17)
#define KOFF 9
#define NENT (KOFF * MRB)        // 1,179,648 total entries

typedef __attribute__((ext_vector_type(8))) short short8;
typedef __attribute__((ext_vector_type(4))) short short4v;
typedef __attribute__((ext_vector_type(4))) float f32x4;
typedef _Float16 f16;
typedef __attribute__((ext_vector_type(2))) _Float16 half2v;
typedef __attribute__((ext_vector_type(4))) _Float16 f16x4;

__device__ __forceinline__ short f2bf(float f) {
    __hip_bfloat16 h = __float2bfloat16(f);
    return __builtin_bit_cast(short, h);
}
__device__ __forceinline__ void atomic_add_f32(float* p, float v) {
    __hip_atomic_fetch_add(p, v, __ATOMIC_RELAXED, __HIP_MEMORY_SCOPE_AGENT);
}

// Packed 2xf16 atomic add: one TCC atomic op covers two channels.
// Same instruction HIP's unsafeAtomicAdd(__half2*) emits on gfx90a+.
#if __has_builtin(__builtin_amdgcn_global_atomic_fadd_v2f16)
typedef __attribute__((address_space(1))) half2v ghalf2;
__device__ __forceinline__ void atomic_pk_add(f16* p, float x, float y) {
    half2v v = {(f16)x, (f16)y};
    __builtin_amdgcn_global_atomic_fadd_v2f16((ghalf2*)p, v);
}
#else
__device__ __forceinline__ void atomic_pk_add(f16* p, float x, float y) {
    half2v v = {(f16)x, (f16)y};
    asm volatile("global_atomic_pk_add_f16 %0, %1, off" :: "v"(p), "v"(v) : "memory");
}
#endif

// ---------------- ws layout (fast path) ----------------
#define FB_OFF   0ull                    // bf16 [NPTS][64]   33,554,432 B
#define WBF_OFF  33554432ull             // bf16 frag-layout W   73,728 B
#define ACC_OFF  33628160ull             // f16  [NPTS][64]   33,554,432 B
#define ACC_BYTES 33554432ull
#define WS_NEED  67182592ull

// ============================================================
// Fast path kernels
// ============================================================

// Grid-stride: coords->float into d_out, feats->bf16, weight->bf16 frags.
__global__ __launch_bounds__(256) void prep(const int*   __restrict__ coords,
                                            const float* __restrict__ feats,
                                            const float* __restrict__ weight,
                                            float* __restrict__ out,
                                            short* __restrict__ fb,
                                            short* __restrict__ wbf) {
    const int T0 = (NPTS * 3) / 4;        // 196608  coords int4
    const int T1 = T0 + NPTS * 16;        // +4194304 feats float4->short4
    const int T2 = T1 + (KOFF * 8 * 64);  // +4608   weight frag groups
    const int stride = gridDim.x * 256;
    for (int i = blockIdx.x * 256 + threadIdx.x; i < T2; i += stride) {
        if (i < T0) {
            int4 c = ((const int4*)coords)[i];
            float4 f;
            f.x = (float)c.x; f.y = (float)c.y; f.z = (float)c.z; f.w = (float)c.w;
            ((float4*)out)[i] = f;
        } else if (i < T1) {
            int j = i - T0;
            float4 f = ((const float4*)feats)[j];
            short4v s;
            s[0] = f2bf(f.x); s[1] = f2bf(f.y); s[2] = f2bf(f.z); s[3] = f2bf(f.w);
            ((short4v*)fb)[j] = s;
        } else {
            int w    = i - T1;            // [0, 4608)
            int lane = w & 63;
            int g    = w >> 6;            // g = k*8 + kk*4 + mt, [0,72)
            int mt   = g & 3, kk = (g >> 2) & 1, k = g >> 3;
            int lhi  = lane >> 4, lrow = lane & 15;
            const float* Wk = weight + k * 64 * 64;
            short8 v;
#pragma unroll
            for (int j = 0; j < 8; ++j)
                v[j] = f2bf(Wk[(kk * 32 + lhi * 8 + j) * 64 + mt * 16 + lrow]);
            ((short8*)wbf)[g * 64 + lane] = v;
        }
    }
}

// Gather-GEMM (transposed D: lane holds one entry, 4 consecutive channels per
// mt) + packed f16 atomic scatter-add into the ws accumulator.
//   wfrag[kk][mt]: one 16-B L1-hot load from pre-laid-out wbf.
//   ffrag: one 16-B load per kk from bf16 feats (gather, 128 B/row).
//   D: col(entry)=lane&15, channel = mt*16 + 4*(lane>>4) + r.
__global__ __launch_bounds__(256) void conv_pk(const short* __restrict__ fb,
                                               const int*   __restrict__ in_rows,
                                               const int*   __restrict__ out_rows,
                                               const short* __restrict__ wbf,
                                               f16*         __restrict__ accum) {
    const int lane = threadIdx.x & 63;
    const int wv   = threadIdx.x >> 6;
    const int lrow = lane & 15;
    const int lhi  = lane >> 4;
    const int BPK  = MRB / 64;                      // 2048 blocks per offset
    const int k    = blockIdx.x / BPK;
    const int mb   = (blockIdx.x % BPK) * 64 + wv * 16;

    short8 wfrag[2][4];
#pragma unroll
    for (int kk = 0; kk < 2; ++kk)
#pragma unroll
        for (int mt = 0; mt < 4; ++mt)
            wfrag[kk][mt] = ((const short8*)wbf)[(k * 8 + kk * 4 + mt) * 64 + lane];

    const int e    = k * MRB + mb + lrow;
    const int arow = in_rows[e];
    const short* ap = fb + (size_t)arow * 64 + lhi * 8;

    f32x4 acc[4] = {};
#pragma unroll
    for (int kk = 0; kk < 2; ++kk) {
        short8 ffrag = *(const short8*)(ap + kk * 32);
#pragma unroll
        for (int mt = 0; mt < 4; ++mt)
            acc[mt] = __builtin_amdgcn_mfma_f32_16x16x32_bf16(wfrag[kk][mt], ffrag, acc[mt], 0, 0, 0);
    }

    const int orow = out_rows[e];
    f16* op = accum + (size_t)orow * 64 + lhi * 4;  // 4 consecutive channels
#pragma unroll
    for (int mt = 0; mt < 4; ++mt) {
        atomic_pk_add(op + mt * 16,     acc[mt][0], acc[mt][1]);
        atomic_pk_add(op + mt * 16 + 2, acc[mt][2], acc[mt][3]);
    }
}

// f16 accumulator -> f32 output + bias.  Layout is linear: row*64 + q*4 = 4*i.
__global__ __launch_bounds__(256) void finalize(const f16* __restrict__ accum,
                                                const float* __restrict__ bias,
                                                float* __restrict__ out) {
    const int i = blockIdx.x * 256 + threadIdx.x;   // grid 16384 -> NPTS*16 exact
    f16x4 v = ((const f16x4*)accum)[i];
    float4 b = ((const float4*)bias)[i & 15];
    float4 o;
    o.x = (float)v[0] + b.x;
    o.y = (float)v[1] + b.y;
    o.z = (float)v[2] + b.z;
    o.w = (float)v[3] + b.w;
    ((float4*)out)[i] = o;
}

// ============================================================
// Fallback path (round-1 verified): scalar-atomic scatter
// ============================================================
__global__ __launch_bounds__(256) void init_full(const int* __restrict__ coords,
                                                 const float* __restrict__ bias,
                                                 float* __restrict__ out) {
    const int tid = blockIdx.x * blockDim.x + threadIdx.x;
    const int nc4 = (NPTS * 3) / 4;
    const int nf4 = (NPTS * 64) / 4;
    for (int i = tid; i < nc4 + nf4; i += gridDim.x * blockDim.x) {
        if (i < nc4) {
            int4 c = ((const int4*)coords)[i];
            float4 f;
            f.x = (float)c.x; f.y = (float)c.y; f.z = (float)c.z; f.w = (float)c.w;
            ((float4*)out)[i] = f;
        } else {
            int j = i - nc4;
            float4 b = ((const float4*)bias)[j & 15];
            ((float4*)(out + (size_t)NPTS * 3))[j] = b;
        }
    }
}

__global__ __launch_bounds__(256) void conv_atomic(const float* __restrict__ feats,
                                                   const int*   __restrict__ in_rows,
                                                   const int*   __restrict__ out_rows,
                                                   const float* __restrict__ weight,
                                                   float*       __restrict__ out) {
    const int lane = threadIdx.x & 63;
    const int wv   = threadIdx.x >> 6;
    const int lrow = lane & 15;
    const int lhi  = lane >> 4;
    const int BPK  = MRB / 64;
    const int k    = blockIdx.x / BPK;
    const int mb   = (blockIdx.x % BPK) * 64 + wv * 16;

    const float* Wk = weight + k * 64 * 64;
    short8 bfrag[2][4];
#pragma unroll
    for (int kk = 0; kk < 2; ++kk)
#pragma unroll
        for (int nt = 0; nt < 4; ++nt)
#pragma unroll
            for (int j = 0; j < 8; ++j)
                bfrag[kk][nt][j] = f2bf(Wk[(kk * 32 + lhi * 8 + j) * 64 + nt * 16 + lrow]);

    const int arow = in_rows[k * MRB + mb + lrow];
    const float* ap = feats + (long)arow * 64 + lhi * 8;

    f32x4 acc[4] = {};
#pragma unroll
    for (int kk = 0; kk < 2; ++kk) {
        float4 f0 = *(const float4*)(ap + kk * 32);
        float4 f1 = *(const float4*)(ap + kk * 32 + 4);
        short8 afrag;
        afrag[0] = f2bf(f0.x); afrag[1] = f2bf(f0.y);
        afrag[2] = f2bf(f0.z); afrag[3] = f2bf(f0.w);
        afrag[4] = f2bf(f1.x); afrag[5] = f2bf(f1.y);
        afrag[6] = f2bf(f1.z); afrag[7] = f2bf(f1.w);
#pragma unroll
        for (int nt = 0; nt < 4; ++nt)
            acc[nt] = __builtin_amdgcn_mfma_f32_16x16x32_bf16(afrag, bfrag[kk][nt], acc[nt], 0, 0, 0);
    }

    const int ob = k * MRB + mb + lhi * 4;
#pragma unroll
    for (int r = 0; r < 4; ++r) {
        const int orow = out_rows[ob + r];
        float* op = out + (long)orow * 64 + lrow;
#pragma unroll
        for (int nt = 0; nt < 4; ++nt)
            atomic_add_f32(op + nt * 16, acc[nt][r]);
    }
}

// ============================================================
extern "C" void kernel_launch(void* const* d_in, const int* in_sizes, int n_in,
                              void* d_out, int out_size, void* d_ws, size_t ws_size,
                              hipStream_t stream) {
    const int*   coords   = (const int*)  d_in[0];
    const float* feats    = (const float*)d_in[1];
    const int*   in_rows  = (const int*)  d_in[2];
    const int*   out_rows = (const int*)  d_in[3];
    const float* weight   = (const float*)d_in[4];
    const float* bias     = (const float*)d_in[5];
    float* out      = (float*)d_out;
    float* out_feat = out + (size_t)NPTS * 3;

    if (ws_size >= WS_NEED) {
        char* ws = (char*)d_ws;
        short* fb    = (short*)(ws + FB_OFF);
        short* wbf   = (short*)(ws + WBF_OFF);
        f16*   accum = (f16*)(ws + ACC_OFF);

        hipMemsetAsync(accum, 0, ACC_BYTES, stream);
        hipLaunchKernelGGL(prep,     dim3(2048), dim3(256), 0, stream,
                           coords, feats, weight, out, fb, wbf);
        hipLaunchKernelGGL(conv_pk,  dim3(KOFF * (MRB / 64)), dim3(256), 0, stream,
                           fb, in_rows, out_rows, wbf, accum);
        hipLaunchKernelGGL(finalize, dim3(NPTS / 16), dim3(256), 0, stream,
                           accum, bias, out_feat);
    } else {
        hipLaunchKernelGGL(init_full,   dim3(2048), dim3(256), 0, stream, coords, bias, out);
        hipLaunchKernelGGL(conv_atomic, dim3(KOFF * (MRB / 64)), dim3(256), 0, stream,
                           feats, in_rows, out_rows, weight, out_feat);
    }
}